// Round 9
// baseline (290.531 us; speedup 1.0000x reference)
//
#include <hip/hip_runtime.h>

// Problem constants (B=16, T=2048 fixed by setup_inputs)
constexpr int NB = 16;
constexpr int NT = 2048;
constexpr int KPROP = 2000;
constexpr int CAP = 4096;       // candidate cap (expected n ~= 2000 + ~12)
constexpr int TIE_CAP = 2048;

// ---------------------------------------------------------------------------
// ws layout (bytes):
//   0      : gMode[16] int   (1 = threshold scatter, 2 = all-candidates <K case)
//   64     : gV32[16]  u32   (exact 32-bit K-th score bit pattern)
//   128    : gNd2[16]  int   (ties at V32 still to keep)
//   192    : gCnt[16]  int   (candidate count)
//   4096   : candFlat[16][4096] u32  (flat = s*2048+e)
//   266240 : candBits[16][4096] u32  (score bit pattern)
// ---------------------------------------------------------------------------

// Descending scan over nbuck-bucket histogram (nbuck = 2048 or 1024):
// find bucket where cumulative-from-top first reaches nd. oB=-1 iff total<nd.
__device__ void dscan(const unsigned* __restrict__ h, int nbuck, int nd, int tid,
                      int* cs, int* oB, int* oNd, int* oTot) {
    int chunk = nbuck >> 8;
    if (tid < 256) {
        int base = tid * chunk, s2 = 0;
        for (int c = 0; c < chunk; c++) s2 += (int)h[base + c];
        cs[tid] = s2;
    }
    __syncthreads();
    if (tid == 0) {
        int tot = 0;
        for (int t2 = 0; t2 < 256; t2++) tot += cs[t2];
        int acc = 0, tc = -1;
        for (int t2 = 255; t2 >= 0; t2--) {
            if (acc + cs[t2] >= nd) { tc = t2; break; }
            acc += cs[t2];
        }
        int found = -1;
        if (tc >= 0) {
            for (int c = tc * chunk + chunk - 1; c >= tc * chunk; c--) {
                int cnt = (int)h[c];
                if (acc + cnt >= nd) { found = c; break; }
                acc += cnt;
            }
        }
        *oB = found;
        *oNd = nd - acc;               // in [1, h[found]] when found >= 0
        if (oTot) *oTot = tot;
    }
    __syncthreads();
}

// K1: blocks [16, 2064) zero the 268 MB output. Blocks [0,16): one batch each,
// 512 threads: select (R7-verified) -> per-row j0 (parallel binary searches)
// -> value-linear pair histogram (uniform bucket spread, no hot-bucket
// serialization) -> collect ~2.4K candidates -> exact 3-level bit refinement
// (R8-verified logic) -> persist (flat,bits)+threshold for K2.
__global__ __launch_bounds__(512) void k_main(
        const float* __restrict__ start, const float* __restrict__ end,
        float4* __restrict__ out4,
        int* __restrict__ gMode, unsigned* __restrict__ gV32,
        int* __restrict__ gNd2, int* __restrict__ gCnt,
        unsigned* __restrict__ candFlat, unsigned* __restrict__ candBits) {
    int blk = blockIdx.x, tid = threadIdx.x;
    if (blk >= NB) {                     // ---- fill path: 131072 B per block ----
        float4 z = make_float4(0.f, 0.f, 0.f, 0.f);
        size_t base = (size_t)(blk - NB) * 8192 + tid;
        #pragma unroll
        for (int it = 0; it < 16; it++) out4[base + (size_t)it * 512] = z;
        return;
    }
    int b = blk;
    __shared__ int   lsI[NT]; __shared__ float lsV[NT];
    __shared__ int   leI[NT]; __shared__ float leV[NT];
    __shared__ short j0s[NT];
    __shared__ unsigned hist[2048];
    __shared__ unsigned candL[CAP];
    __shared__ float red2[2][256];
    __shared__ int   sc2[2][256];
    __shared__ int   cs[256];
    __shared__ int   sN[2];
    __shared__ float sMax[2];
    __shared__ int   scnt, sB, sNd, sTot;

    // ---------- select (R7-verified, two 256-thread halves) ----------
    int w = tid >> 8, t = tid & 255;
    const float* p = (w ? end : start) + (size_t)b * NT;
    int*   oI = w ? leI : lsI;
    float* oV = w ? leV : lsV;

    int t0 = t * 8;
    float v[8];
    *(float4*)&v[0] = *(const float4*)&p[t0];
    *(float4*)&v[4] = *(const float4*)&p[t0 + 4];

    float m = v[0];
    #pragma unroll
    for (int k = 1; k < 8; k++) m = fmaxf(m, v[k]);
    red2[w][t] = m;
    __syncthreads();
    for (int s = 128; s > 0; s >>= 1) {
        if (t < s) red2[w][t] = fmaxf(red2[w][t], red2[w][t + s]);
        __syncthreads();
    }
    float thr = 0.5f * red2[w][0];
    if (t == 0) sMax[w] = red2[w][0];

    float prev = (t == 0)   ? -1.0f : p[t0 - 1];   // t==0: rise pad true
    float next = (t == 255) ? -1.0f : p[t0 + 8];   // t==2047: fall pad true

    bool flag[8];
    int c = 0;
    #pragma unroll
    for (int k = 0; k < 8; k++) {
        float pv = (k == 0) ? prev : v[k - 1];
        float nv = (k == 7) ? next : v[k + 1];
        bool f = ((v[k] > pv) && (v[k] > nv)) || (v[k] > thr);
        flag[k] = f;
        c += f;
    }
    sc2[w][t] = c;
    __syncthreads();
    for (int off = 1; off < 256; off <<= 1) {      // Hillis-Steele inclusive scan
        int val = (t >= off) ? sc2[w][t - off] : 0;
        __syncthreads();
        sc2[w][t] += val;
        __syncthreads();
    }
    int pos = sc2[w][t] - c;                       // exclusive offset
    #pragma unroll
    for (int k = 0; k < 8; k++)
        if (flag[k]) { oI[pos] = t0 + k; oV[pos] = v[k]; pos++; }
    if (t == 255) sN[w] = sc2[w][255];
    __syncthreads();

    int mS = sN[0], mE = sN[1];

    // ---------- per-row j0: first j with leI[j] >= lsI[i] (thread-parallel) ----------
    for (int i = tid; i < mS; i += 512) {
        int s = lsI[i];
        int lo = 0, hi = mE;
        while (lo < hi) { int mid = (lo + hi) >> 1; if (leI[mid] < s) lo = mid + 1; else hi = mid; }
        j0s[i] = (short)lo;
    }
    for (int cc = tid; cc < 2048; cc += 512) hist[cc] = 0u;
    if (tid == 0) scnt = 0;
    __syncthreads();

    // ---------- pass A: value-linear histogram over valid pairs ----------
    float maxP = sMax[0] * sMax[1];
    float scale = (maxP > 0.f) ? 2047.0f / maxP : 0.f;
    int wv = tid >> 6, ln = tid & 63;
    for (int i = wv; i < mS; i += 8) {
        float x = lsV[i];
        int jb = j0s[i];
        for (int j = jb + ln; j < mE; j += 64) {
            float prod = x * leV[j];
            int key = (int)(prod * scale);
            key = key > 2047 ? 2047 : (key < 0 ? 0 : key);
            atomicAdd(&hist[key], 1u);
        }
    }
    __syncthreads();
    dscan(hist, 2048, KPROP, tid, cs, &sB, &sNd, &sTot);
    int v0 = sB, tot = sTot;
    bool mode2 = (tot < KPROP);          // includes v0<0
    bool bitMode = false;

    if (!mode2) {
        int above = KPROP - sNd;
        int inB = (int)hist[v0];
        if (above + inB > CAP) {         // fat bucket (ties/clusters): bit-mode fallback
            bitMode = true;
            __syncthreads();
            for (int cc = tid; cc < 2048; cc += 512) hist[cc] = 0u;
            __syncthreads();
            for (int i = wv; i < mS; i += 8) {
                float x = lsV[i];
                int jb = j0s[i];
                for (int j = jb + ln; j < mE; j += 64) {
                    unsigned bits = __float_as_uint(x * leV[j]);
                    atomicAdd(&hist[bits >> 20], 1u);
                }
            }
            __syncthreads();
            dscan(hist, 2048, KPROP, tid, cs, &sB, &sNd, nullptr);
            v0 = sB;
        }
    }
    __syncthreads();

    // ---------- pass B: collect candidates ----------
    for (int i = wv; i < mS; i += 8) {
        float x = lsV[i];
        int jb = j0s[i];
        for (int j = jb + ln; j < mE; j += 64) {
            float prod = x * leV[j];
            bool take;
            if (mode2)        take = true;
            else if (bitMode) take = (__float_as_uint(prod) >> 20) >= (unsigned)v0;
            else {
                int key = (int)(prod * scale);
                key = key > 2047 ? 2047 : (key < 0 ? 0 : key);
                take = key >= v0;
            }
            if (take) {
                int pp = atomicAdd(&scnt, 1);
                if (pp < CAP) candL[pp] = ((unsigned)i << 11) | (unsigned)j;
            }
        }
    }
    __syncthreads();
    int n = min(scnt, CAP);

    if (mode2) {                          // <K valid pairs: all candidates win
        for (int k = tid; k < n; k += 512) {
            unsigned ij = candL[k];
            int i = ij >> 11, j = ij & 2047;
            candFlat[b * CAP + k] = (unsigned)(lsI[i] * NT + leI[j]);
        }
        if (tid == 0) { gMode[b] = 2; gCnt[b] = n; }
        return;
    }

    // ---------- exact 3-level bit refinement among candidates (R8-verified) ----------
    // level A: bits[30:20] (2048 buckets), nd starts at KPROP (candidates ⊇ top-K)
    for (int cc = tid; cc < 2048; cc += 512) hist[cc] = 0u;
    __syncthreads();
    for (int k = tid; k < n; k += 512) {
        unsigned ij = candL[k];
        unsigned bits = __float_as_uint(lsV[ij >> 11] * leV[ij & 2047]);
        atomicAdd(&hist[bits >> 20], 1u);
    }
    __syncthreads();
    dscan(hist, 2048, KPROP, tid, cs, &sB, &sNd, nullptr);
    unsigned bA = (unsigned)sB;
    int ndA = sNd;

    // level B: bits[19:10] within bucket bA (1024 buckets)
    __syncthreads();
    for (int cc = tid; cc < 1024; cc += 512) hist[cc] = 0u;
    __syncthreads();
    for (int k = tid; k < n; k += 512) {
        unsigned ij = candL[k];
        unsigned bits = __float_as_uint(lsV[ij >> 11] * leV[ij & 2047]);
        if ((bits >> 20) == bA) atomicAdd(&hist[(bits >> 10) & 1023], 1u);
    }
    __syncthreads();
    dscan(hist, 1024, ndA, tid, cs, &sB, &sNd, nullptr);
    unsigned pref20 = (bA << 10) | (unsigned)sB;
    int ndB = sNd;

    // level C: bits[9:0] within prefix
    __syncthreads();
    for (int cc = tid; cc < 1024; cc += 512) hist[cc] = 0u;
    __syncthreads();
    for (int k = tid; k < n; k += 512) {
        unsigned ij = candL[k];
        unsigned bits = __float_as_uint(lsV[ij >> 11] * leV[ij & 2047]);
        if ((bits >> 10) == pref20) atomicAdd(&hist[bits & 1023], 1u);
    }
    __syncthreads();
    dscan(hist, 1024, ndB, tid, cs, &sB, &sNd, nullptr);
    unsigned V32 = (pref20 << 10) | (unsigned)sB;   // exact K-th score bits
    int nd2 = sNd;                                  // ties to keep at V32

    // ---------- persist for K2 ----------
    for (int k = tid; k < n; k += 512) {
        unsigned ij = candL[k];
        int i = ij >> 11, j = ij & 2047;
        candFlat[b * CAP + k] = (unsigned)(lsI[i] * NT + leI[j]);
        candBits[b * CAP + k] = __float_as_uint(lsV[i] * leV[j]);
    }
    if (tid == 0) { gMode[b] = 1; gV32[b] = V32; gNd2[b] = nd2; gCnt[b] = n; }
}

// K2: scatter 1.0s, strictly after K1's fill. mode 1: bits > V32 win, plus the
// nd2 lowest-flat ties == V32 (lax.top_k order). mode 2: all candidates win.
__global__ __launch_bounds__(512) void k_emit(
        const int* __restrict__ gMode, const unsigned* __restrict__ gV32,
        const int* __restrict__ gNd2, const int* __restrict__ gCnt,
        const unsigned* __restrict__ candFlat, const unsigned* __restrict__ candBits,
        float* __restrict__ out) {
    int b = blockIdx.x, tid = threadIdx.x;
    int md = gMode[b], n = gCnt[b];
    const unsigned* cf = candFlat + b * CAP;

    if (md == 2) {
        for (int k = tid; k < n; k += 512) {
            unsigned f = cf[k];
            int s = (int)(f >> 11), e = (int)(f & 2047u);
            out[((size_t)b * NT + (e - s)) * NT + s] = 1.0f;
        }
        return;
    }

    __shared__ unsigned tie[TIE_CAP];
    __shared__ int tieCnt;
    if (tid == 0) tieCnt = 0;
    __syncthreads();

    unsigned V32 = gV32[b];
    int nd2 = gNd2[b];
    const unsigned* cb = candBits + b * CAP;

    for (int k = tid; k < n; k += 512) {
        unsigned bits = cb[k];
        unsigned f = cf[k];
        if (bits > V32) {
            int s = (int)(f >> 11), e = (int)(f & 2047u);
            out[((size_t)b * NT + (e - s)) * NT + s] = 1.0f;
        } else if (bits == V32) {
            int pp = atomicAdd(&tieCnt, 1);
            if (pp < TIE_CAP) tie[pp] = f;
        }
    }
    __syncthreads();
    int tn = min(tieCnt, TIE_CAP);
    for (int k = tid; k < tn; k += 512) {
        unsigned f = tie[k];
        int rank = 0;
        for (int j = 0; j < tn; j++) rank += (tie[j] < f) ? 1 : 0;
        if (rank < nd2) {                 // lowest flat indices win (lax.top_k)
            int s = (int)(f >> 11), e = (int)(f & 2047u);
            out[((size_t)b * NT + (e - s)) * NT + s] = 1.0f;
        }
    }
}

extern "C" void kernel_launch(void* const* d_in, const int* in_sizes, int n_in,
                              void* d_out, int out_size, void* d_ws, size_t ws_size,
                              hipStream_t stream) {
    const float* start = (const float*)d_in[0];
    const float* end   = (const float*)d_in[1];
    // d_in[2] (actionness) unused by the reference.
    float* out = (float*)d_out;
    char* ws = (char*)d_ws;

    int*      gMode    = (int*)     (ws + 0);
    unsigned* gV32     = (unsigned*)(ws + 64);
    int*      gNd2     = (int*)     (ws + 128);
    int*      gCnt     = (int*)     (ws + 192);
    unsigned* candFlat = (unsigned*)(ws + 4096);
    unsigned* candBits = (unsigned*)(ws + 266240);

    // K1: 16 per-batch work blocks + 2048 fill blocks (268 MB zero);
    //     per-batch work (~30 µs) hides under the fill (~40 µs).
    k_main<<<NB + 2048, 512, 0, stream>>>(start, end, (float4*)out,
                                          gMode, gV32, gNd2, gCnt,
                                          candFlat, candBits);
    // K2: scatter winners/ties, strictly after the fill completes.
    k_emit<<<NB, 512, 0, stream>>>(gMode, gV32, gNd2, gCnt, candFlat, candBits, out);
}

// Round 10
// 147.315 us; speedup vs baseline: 1.9722x; 1.9722x over previous
//
#include <hip/hip_runtime.h>

// Problem constants (B=16, T=2048 fixed by setup_inputs)
constexpr int NB = 16;
constexpr int NT = 2048;
constexpr int KPROP = 2000;
constexpr int CAP = 8192;       // candidate cap; primary path guarantees n <= CAP
constexpr int TIE_CAP = 2048;

// ---------------------------------------------------------------------------
// ws layout (bytes):
//   0      : gMode[16] int   (1 = threshold scatter, 2 = all-candidates)
//   64     : gV32[16]  u32   (exact 32-bit K-th score bit pattern)
//   128    : gNd2[16]  int   (ties at V32 still to keep)
//   192    : gCnt[16]  int   (candidate count)
//   4096   : candFlat[16][8192] u32  (flat = s*2048+e)      512 KB
//   528384 : candBits[16][8192] u32  (score bit pattern)    512 KB
// ---------------------------------------------------------------------------

// Descending scan over nbuck-bucket histogram: find bucket where cumulative-
// from-top first reaches nd. oB=-1 iff total < nd.  [verified R9]
__device__ void dscan(const unsigned* __restrict__ h, int nbuck, int nd, int tid,
                      int* cs, int* oB, int* oNd) {
    int chunk = nbuck >> 8;
    if (tid < 256) {
        int base = tid * chunk, s2 = 0;
        for (int c = 0; c < chunk; c++) s2 += (int)h[base + c];
        cs[tid] = s2;
    }
    __syncthreads();
    if (tid == 0) {
        int acc = 0, tc = -1;
        for (int t2 = 255; t2 >= 0; t2--) {
            if (acc + cs[t2] >= nd) { tc = t2; break; }
            acc += cs[t2];
        }
        int found = -1;
        if (tc >= 0) {
            for (int c = tc * chunk + chunk - 1; c >= tc * chunk; c--) {
                int cnt = (int)h[c];
                if (acc + cnt >= nd) { found = c; break; }
                acc += cnt;
            }
        }
        *oB = found;
        *oNd = nd - acc;
    }
    __syncthreads();
}

// K1: blocks [16, 2064) zero the 268 MB output. Blocks [0,16): one batch each:
// select (R9-verified) -> bitonic sort e-anchors by value desc -> bisect a
// certified pre-threshold tau (count_all oracle, binary searches only) ->
// enumerate only pairs >= tau (visits <= 8192, early-break on sorted order)
// -> exact 3-level bit refinement (R9-verified dscan) -> persist for K2.
__global__ __launch_bounds__(512) void k_main(
        const float* __restrict__ start, const float* __restrict__ end,
        float4* __restrict__ out4,
        int* __restrict__ gMode, unsigned* __restrict__ gV32,
        int* __restrict__ gNd2, int* __restrict__ gCnt,
        unsigned* __restrict__ candFlat, unsigned* __restrict__ candBits) {
    int blk = blockIdx.x, tid = threadIdx.x;
    if (blk >= NB) {                     // ---- fill path: 131072 B per block ----
        float4 z = make_float4(0.f, 0.f, 0.f, 0.f);
        size_t base = (size_t)(blk - NB) * 8192 + tid;
        #pragma unroll
        for (int it = 0; it < 16; it++) out4[base + (size_t)it * 512] = z;
        return;
    }
    int b = blk;
    size_t bc = (size_t)b * CAP;

    __shared__ short lsI[NT];  __shared__ float lsV[NT];
    __shared__ short leI[NT];                       // e positions, index-sorted
    __shared__ float evV[NT];  __shared__ short evI[NT];  // value-sorted desc
    __shared__ short j0s[NT];
    __shared__ unsigned hist[2048];
    __shared__ float redF[512];
    __shared__ int   redI[512];
    __shared__ int   sc2[2][256];
    __shared__ int   cs[256];
    __shared__ float sMax[2];
    __shared__ int   sN[2];
    __shared__ int   scnt, sB, sNd;

    // ---------- select (R9-verified logic, two 256-thread halves) ----------
    int w = tid >> 8, t = tid & 255;
    const float* p = (w ? end : start) + (size_t)b * NT;

    int t0 = t * 8;
    float v[8];
    *(float4*)&v[0] = *(const float4*)&p[t0];
    *(float4*)&v[4] = *(const float4*)&p[t0 + 4];

    float m = v[0];
    #pragma unroll
    for (int k = 1; k < 8; k++) m = fmaxf(m, v[k]);
    redF[w * 256 + t] = m;
    __syncthreads();
    for (int s = 128; s > 0; s >>= 1) {
        if (t < s) redF[w * 256 + t] = fmaxf(redF[w * 256 + t], redF[w * 256 + t + s]);
        __syncthreads();
    }
    float thr = 0.5f * redF[w * 256];
    if (t == 0) sMax[w] = redF[w * 256];

    float prev = (t == 0)   ? -1.0f : p[t0 - 1];   // t==0: rise pad true
    float next = (t == 255) ? -1.0f : p[t0 + 8];   // t==2047: fall pad true

    bool flag[8];
    int c = 0;
    #pragma unroll
    for (int k = 0; k < 8; k++) {
        float pv = (k == 0) ? prev : v[k - 1];
        float nv = (k == 7) ? next : v[k + 1];
        bool f = ((v[k] > pv) && (v[k] > nv)) || (v[k] > thr);
        flag[k] = f;
        c += f;
    }
    sc2[w][t] = c;
    __syncthreads();
    for (int off = 1; off < 256; off <<= 1) {      // Hillis-Steele inclusive scan
        int val = (t >= off) ? sc2[w][t - off] : 0;
        __syncthreads();
        sc2[w][t] += val;
        __syncthreads();
    }
    int pos = sc2[w][t] - c;
    #pragma unroll
    for (int k = 0; k < 8; k++) {
        if (flag[k]) {
            if (w == 0) { lsI[pos] = (short)(t0 + k); lsV[pos] = v[k]; }
            else        { leI[pos] = (short)(t0 + k); evV[pos] = v[k]; }
            pos++;
        }
    }
    if (t == 255) sN[w] = sc2[w][255];
    __syncthreads();

    int mS = sN[0], mE = sN[1];

    // ---------- pad + seed value-sort arrays ----------
    for (int k = tid; k < NT; k += 512) {
        if (k < mE) evI[k] = leI[k];
        else { evV[k] = -1.0f; evI[k] = 0; }
    }
    __syncthreads();

    // ---------- bitonic sort (evV desc, evI carried) ----------
    for (int kk = 2; kk <= NT; kk <<= 1) {
        for (int jj = kk >> 1; jj > 0; jj >>= 1) {
            for (int base = tid; base < NT; base += 512) {
                int partner = base ^ jj;
                if (partner > base) {
                    bool descBlk = ((base & kk) == 0);
                    float a = evV[base], bv = evV[partner];
                    bool doSwap = descBlk ? (a < bv) : (a > bv);
                    if (doSwap) {
                        evV[base] = bv; evV[partner] = a;
                        short ti = evI[base]; evI[base] = evI[partner]; evI[partner] = ti;
                    }
                }
            }
            __syncthreads();
        }
    }

    // ---------- j0s (validity base) + totalValid ----------
    int myTot = 0;
    for (int i = tid; i < mS; i += 512) {
        int sPos = lsI[i];
        int lo2 = 0, hi2 = mE;
        while (lo2 < hi2) { int mid = (lo2 + hi2) >> 1; if (leI[mid] < sPos) lo2 = mid + 1; else hi2 = mid; }
        j0s[i] = (short)lo2;
        myTot += mE - lo2;
    }
    redI[tid] = myTot;
    __syncthreads();
    for (int s = 256; s > 0; s >>= 1) {
        if (tid < s) redI[tid] += redI[tid + s];
        __syncthreads();
    }
    int totalValid = redI[0];
    __syncthreads();

    int wv = tid >> 6, ln = tid & 63;

    // ---------- mode 2: fewer than K valid pairs -> all valid pairs win ----------
    if (totalValid < KPROP) {
        if (tid == 0) scnt = 0;
        __syncthreads();
        for (int i = wv; i < mS; i += 8) {
            int sPos = lsI[i];
            for (int base = j0s[i]; base < mE; base += 64) {
                int j = base + ln;
                bool tk = (j < mE);
                unsigned long long vm = __ballot(tk);
                int cntv = __popcll(vm);
                int bw = 0;
                if (ln == 0) bw = atomicAdd(&scnt, cntv);
                bw = __shfl(bw, 0);
                if (tk) {
                    int p2 = bw + __popcll(vm & ((1ull << ln) - 1ull));
                    if (p2 < CAP) candFlat[bc + p2] = (unsigned)((lsI[i] << 11) | (int)leI[j]);
                }
            }
        }
        __syncthreads();
        if (tid == 0) { gMode[b] = 2; gCnt[b] = min(scnt, CAP); }
        return;
    }

    // ---------- min-value reduces -> bisect domain ----------
    float mn = 3.4e38f;
    for (int i = tid; i < mS; i += 512) mn = fminf(mn, lsV[i]);
    redF[tid] = mn;
    __syncthreads();
    for (int s = 256; s > 0; s >>= 1) {
        if (tid < s) redF[tid] = fminf(redF[tid], redF[tid + s]);
        __syncthreads();
    }
    float minSv = redF[0];
    __syncthreads();
    mn = 3.4e38f;
    for (int i = tid; i < mE; i += 512) mn = fminf(mn, evV[i]);
    redF[tid] = mn;
    __syncthreads();
    for (int s = 256; s > 0; s >>= 1) {
        if (tid < s) redF[tid] = fminf(redF[tid], redF[tid + s]);
        __syncthreads();
    }
    float loProd = redF[0] * minSv;
    __syncthreads();
    float hiProd = sMax[0] * sMax[1];

    // count_all(tau): per-s-anchor binary search in descending evV
    auto countAll = [&](float tau) -> int {
        int myc = 0;
        for (int i = tid; i < mS; i += 512) {
            float svv = lsV[i];
            int lo2 = 0, hi2 = mE;
            while (lo2 < hi2) { int mid = (lo2 + hi2) >> 1; if (svv * evV[mid] >= tau) lo2 = mid + 1; else hi2 = mid; }
            myc += lo2;
        }
        redI[tid] = myc;
        __syncthreads();
        for (int s = 256; s > 0; s >>= 1) {
            if (tid < s) redI[tid] += redI[tid + s];
            __syncthreads();
        }
        int r = redI[0];
        __syncthreads();
        return r;
    };

    // walk(tau): enumerate pairs >= tau via descending e-walk with early break.
    // store=true also writes candFlat/candBits. Returns count_valid(tau).
    auto walk = [&](float tau, bool store) -> int {
        if (tid == 0) scnt = 0;
        __syncthreads();
        for (int i = wv; i < mS; i += 8) {
            int sPos = lsI[i];
            float svv = lsV[i];
            for (int base = 0; base < NT; base += 64) {
                int k = base + ln;
                float prod = svv * evV[k];
                bool ge = (prod >= tau) && (k < mE);
                bool valid = ge && ((int)evI[k] >= sPos);
                unsigned long long vm = __ballot(valid);
                int cntv = __popcll(vm);
                if (cntv) {
                    int bw = 0;
                    if (ln == 0) bw = atomicAdd(&scnt, cntv);
                    bw = __shfl(bw, 0);
                    if (store && valid) {
                        int p2 = bw + __popcll(vm & ((1ull << ln) - 1ull));
                        if (p2 < CAP) {
                            candFlat[bc + p2] = (unsigned)((sPos << 11) | (int)evI[k]);
                            candBits[bc + p2] = __float_as_uint(prod);
                        }
                    }
                }
                if (__popcll(__ballot(ge)) < 64) break;   // desc order: done with row
            }
        }
        __syncthreads();
        int r = scnt;
        __syncthreads();
        return r;
    };

    // ---------- bisect tau on count_all into [6000, 8192] ----------
    float a = loProd, bHi = hiProd, tauSel = -1.0f;
    for (int it = 0; it < 20; it++) {
        float mid = 0.5f * (a + bHi);
        int cnt = countAll(mid);
        if (cnt > CAP) a = mid;
        else { bHi = mid; tauSel = mid; if (cnt >= 6000) break; }
    }
    if (tauSel < 0.0f) tauSel = hiProd;

    // ---------- collect; certify count_valid >= K (retry bisect if not) ----------
    int n = walk(tauSel, true);
    if (n < KPROP) {
        float a2 = loProd, b2 = tauSel, tauOK = -1.0f;
        for (int it = 0; it < 10; it++) {
            float mid = 0.5f * (a2 + b2);
            int cv = walk(mid, false);
            if (cv < KPROP) b2 = mid;
            else if (cv > CAP) a2 = mid;
            else { tauOK = mid; break; }
        }
        if (tauOK < 0.0f) tauOK = a2;      // degrade only on tie-storm pathology
        n = walk(tauOK, true);
        if (n > CAP) n = CAP;
    }

    if (n < KPROP) {                        // unreachable on sane inputs
        if (tid == 0) { gMode[b] = 2; gCnt[b] = n; }
        return;
    }

    // ---------- exact 3-level bit refinement among candidates (R9-verified) ----------
    // level A: bits[30:20]
    for (int cc = tid; cc < 2048; cc += 512) hist[cc] = 0u;
    __syncthreads();
    for (int k = tid; k < n; k += 512) atomicAdd(&hist[candBits[bc + k] >> 20], 1u);
    __syncthreads();
    dscan(hist, 2048, KPROP, tid, cs, &sB, &sNd);
    unsigned bA = (unsigned)sB;
    int ndA = sNd;
    __syncthreads();

    // level B: bits[19:10] within bucket bA
    for (int cc = tid; cc < 1024; cc += 512) hist[cc] = 0u;
    __syncthreads();
    for (int k = tid; k < n; k += 512) {
        unsigned bits = candBits[bc + k];
        if ((bits >> 20) == bA) atomicAdd(&hist[(bits >> 10) & 1023], 1u);
    }
    __syncthreads();
    dscan(hist, 1024, ndA, tid, cs, &sB, &sNd);
    unsigned pref20 = (bA << 10) | (unsigned)sB;
    int ndB = sNd;
    __syncthreads();

    // level C: bits[9:0] within prefix
    for (int cc = tid; cc < 1024; cc += 512) hist[cc] = 0u;
    __syncthreads();
    for (int k = tid; k < n; k += 512) {
        unsigned bits = candBits[bc + k];
        if ((bits >> 10) == pref20) atomicAdd(&hist[bits & 1023], 1u);
    }
    __syncthreads();
    dscan(hist, 1024, ndB, tid, cs, &sB, &sNd);

    if (tid == 0) {
        gV32[b] = (pref20 << 10) | (unsigned)sB;   // exact K-th score bits
        gNd2[b] = sNd;                             // ties to keep at V32
        gMode[b] = 1;
        gCnt[b]  = n;
    }
}

// K2: scatter 1.0s, strictly after K1's fill. mode 1: bits > V32 win, plus the
// nd2 lowest-flat ties == V32 (lax.top_k order). mode 2: all candidates win.
// [verified R9]
__global__ __launch_bounds__(512) void k_emit(
        const int* __restrict__ gMode, const unsigned* __restrict__ gV32,
        const int* __restrict__ gNd2, const int* __restrict__ gCnt,
        const unsigned* __restrict__ candFlat, const unsigned* __restrict__ candBits,
        float* __restrict__ out) {
    int b = blockIdx.x, tid = threadIdx.x;
    int md = gMode[b], n = gCnt[b];
    const unsigned* cf = candFlat + (size_t)b * CAP;

    if (md == 2) {
        for (int k = tid; k < n; k += 512) {
            unsigned f = cf[k];
            int s = (int)(f >> 11), e = (int)(f & 2047u);
            out[((size_t)b * NT + (e - s)) * NT + s] = 1.0f;
        }
        return;
    }

    __shared__ unsigned tie[TIE_CAP];
    __shared__ int tieCnt;
    if (tid == 0) tieCnt = 0;
    __syncthreads();

    unsigned V32 = gV32[b];
    int nd2 = gNd2[b];
    const unsigned* cb = candBits + (size_t)b * CAP;

    for (int k = tid; k < n; k += 512) {
        unsigned bits = cb[k];
        unsigned f = cf[k];
        if (bits > V32) {
            int s = (int)(f >> 11), e = (int)(f & 2047u);
            out[((size_t)b * NT + (e - s)) * NT + s] = 1.0f;
        } else if (bits == V32) {
            int pp = atomicAdd(&tieCnt, 1);
            if (pp < TIE_CAP) tie[pp] = f;
        }
    }
    __syncthreads();
    int tn = min(tieCnt, TIE_CAP);
    for (int k = tid; k < tn; k += 512) {
        unsigned f = tie[k];
        int rank = 0;
        for (int j = 0; j < tn; j++) rank += (tie[j] < f) ? 1 : 0;
        if (rank < nd2) {                 // lowest flat indices win (lax.top_k)
            int s = (int)(f >> 11), e = (int)(f & 2047u);
            out[((size_t)b * NT + (e - s)) * NT + s] = 1.0f;
        }
    }
}

extern "C" void kernel_launch(void* const* d_in, const int* in_sizes, int n_in,
                              void* d_out, int out_size, void* d_ws, size_t ws_size,
                              hipStream_t stream) {
    const float* start = (const float*)d_in[0];
    const float* end   = (const float*)d_in[1];
    // d_in[2] (actionness) unused by the reference.
    float* out = (float*)d_out;
    char* ws = (char*)d_ws;

    int*      gMode    = (int*)     (ws + 0);
    unsigned* gV32     = (unsigned*)(ws + 64);
    int*      gNd2     = (int*)     (ws + 128);
    int*      gCnt     = (int*)     (ws + 192);
    unsigned* candFlat = (unsigned*)(ws + 4096);
    unsigned* candBits = (unsigned*)(ws + 528384);

    // K1: 16 per-batch work blocks (~30 us) + 2048 fill blocks (268 MB zero)
    k_main<<<NB + 2048, 512, 0, stream>>>(start, end, (float4*)out,
                                          gMode, gV32, gNd2, gCnt,
                                          candFlat, candBits);
    // K2: scatter winners/ties, strictly after the fill completes.
    k_emit<<<NB, 512, 0, stream>>>(gMode, gV32, gNd2, gCnt, candFlat, candBits, out);
}